// Round 4
// baseline (242.529 us; speedup 1.0000x reference)
//
#include <hip/hip_runtime.h>

// CommLayer: y[b,a,e] = tanh( xb[b,a,:]·M[e,:] + S[b,:]·Cn[e,:] ),
//   M = H - C/7, Cn = C/7, S[b] = sum_a xb[b,a,:].
// K=128 fp16 MFMA GEMM, A_aug[m=(b,a)] = [xb | S(b)], B_aug[e] = [M[e] | Cn[e]].
// R9: R8's empty-asm fence was defeated (VGPR still 48): plain loads/compute
// move freely across asm volatile statements, so the compiler re-sank every
// load next to its fence. Fix: make the LOADS themselves asm volatile
// (volatile<->volatile ordering pins all 16 issue slots before the single
// s_waitcnt), then s_waitcnt vmcnt(0) + sched_barrier(0) so no compute hoists
// above the wait (guide rule #18). Forced schedule:
//   16x global_load_dwordx4 -> s_waitcnt vmcnt(0) -> 4 tiles of compute.
// 16 KB of reads in flight per wave. Engagement check: VGPR_Count >= ~100.
// R8's verified win kept: BSTRIDE=144 (288 B = 32 mod 128) -> bank conflicts 0.

typedef _Float16 half4v  __attribute__((ext_vector_type(4)));
typedef _Float16 half8v  __attribute__((ext_vector_type(8)));
typedef float    floatx4 __attribute__((ext_vector_type(4)));

#define WAVES_PER_BLOCK 4
#define TILES_PER_WAVE  4
#define BSTRIDE 144   // halfs per augB row: 128 + 16 pad (288 B = 32 mod 128)

__device__ __forceinline__ half8v h8_bfly_add(half8v v, int mask) {
    union { half8v h; int i[4]; } u, r;
    u.h = v;
    #pragma unroll
    for (int k = 0; k < 4; ++k) r.i[k] = __shfl_xor(u.i[k], mask, 64);
    return v + r.h;   // v_pk_add_f16 x4
}

__global__ __launch_bounds__(256, 4)
void comm_kernel(const float* __restrict__ x,
                 const float* __restrict__ Hw,
                 const float* __restrict__ Cw,
                 float* __restrict__ out)
{
    __shared__ __align__(16) _Float16 augB[64 * BSTRIDE];  // 18432 B

    const int tid  = threadIdx.x;
    const int lane = tid & 63;
    const int wave = tid >> 6;
    const int quad = lane >> 4;   // 0..3
    const int l16  = lane & 15;

    // ---- Stage 0 (once per block): build augmented B in LDS ----
    // augB[e][k<64] = H[e][k] - C[e][k]/7 ; augB[e][64+k] = C[e][k]/7
    #pragma unroll
    for (int i = 0; i < 4; ++i) {
        const int idx = i * 256 + tid;        // 0..1023 float4-chunks
        const int e = idx >> 4;
        const int k = (idx & 15) << 2;
        const float4 h = *reinterpret_cast<const float4*>(Hw + e * 64 + k);
        const float4 c = *reinterpret_cast<const float4*>(Cw + e * 64 + k);
        half4v m4, c4;
        m4[0] = (_Float16)(h.x - c.x * (1.0f / 7.0f)); c4[0] = (_Float16)(c.x * (1.0f / 7.0f));
        m4[1] = (_Float16)(h.y - c.y * (1.0f / 7.0f)); c4[1] = (_Float16)(c.y * (1.0f / 7.0f));
        m4[2] = (_Float16)(h.z - c.z * (1.0f / 7.0f)); c4[2] = (_Float16)(c.z * (1.0f / 7.0f));
        m4[3] = (_Float16)(h.w - c.w * (1.0f / 7.0f)); c4[3] = (_Float16)(c.w * (1.0f / 7.0f));
        *reinterpret_cast<half4v*>(&augB[e * BSTRIDE + k])      = m4;
        *reinterpret_cast<half4v*>(&augB[e * BSTRIDE + 64 + k]) = c4;
    }
    __syncthreads();   // the only barrier

    const int wgid = blockIdx.x * WAVES_PER_BLOCK + wave;
    // Per-lane base for this wave's 4 consecutive tiles.
    const float* xbase = x + (size_t)wgid * TILES_PER_WAVE * 1024 + l16 * 64 + quad * 8;
    float* obase = out + (size_t)wgid * TILES_PER_WAVE * 1024 + l16 * 64 + quad * 4;

    // ---- Issue ALL 16 tile loads as asm volatile: mutually ordered, cannot
    // sink below the (also-volatile) waitcnt. One wait, then stall-free
    // compute. sched_barrier(0) stops VALU/MFMA hoisting above the wait. ----
    floatx4 v[TILES_PER_WAVE][4];
    #pragma unroll
    for (int i = 0; i < TILES_PER_WAVE; ++i) {
        const float* xi = xbase + i * 1024;
        asm volatile("global_load_dwordx4 %0, %1, off"            : "=v"(v[i][0]) : "v"(xi));
        asm volatile("global_load_dwordx4 %0, %1, off offset:16"  : "=v"(v[i][1]) : "v"(xi));
        asm volatile("global_load_dwordx4 %0, %1, off offset:128" : "=v"(v[i][2]) : "v"(xi));
        asm volatile("global_load_dwordx4 %0, %1, off offset:144" : "=v"(v[i][3]) : "v"(xi));
    }
    asm volatile("s_waitcnt vmcnt(0)" ::: "memory");
    __builtin_amdgcn_sched_barrier(0);

    #pragma unroll
    for (int i = 0; i < TILES_PER_WAVE; ++i) {
        // ---- x fragments (B-operand layout: n = l16, k = quad*8 + j) ----
        half8v a0, a1;   // kt=0 (k 0..31), kt=1 (k 32..63)
        a0[0]=(_Float16)v[i][0][0]; a0[1]=(_Float16)v[i][0][1]; a0[2]=(_Float16)v[i][0][2]; a0[3]=(_Float16)v[i][0][3];
        a0[4]=(_Float16)v[i][1][0]; a0[5]=(_Float16)v[i][1][1]; a0[6]=(_Float16)v[i][1][2]; a0[7]=(_Float16)v[i][1][3];
        a1[0]=(_Float16)v[i][2][0]; a1[1]=(_Float16)v[i][2][1]; a1[2]=(_Float16)v[i][2][2]; a1[3]=(_Float16)v[i][2][3];
        a1[4]=(_Float16)v[i][3][0]; a1[5]=(_Float16)v[i][3][1]; a1[6]=(_Float16)v[i][3][2]; a1[7]=(_Float16)v[i][3][3];

        // ---- S via packed fp16 butterfly over the 8 agent-lanes (l16 bits 0..2).
        // Result is broadcast to every lane = kt=2,3 augmented fragment. ----
        half8v s0 = a0, s1 = a1;
        #pragma unroll
        for (int m = 1; m <= 4; m <<= 1) {
            s0 = h8_bfly_add(s0, m);
            s1 = h8_bfly_add(s1, m);
        }

        // ---- MFMA, transposed: weights as A-operand ----
        floatx4 acc[4];
        #pragma unroll
        for (int nt = 0; nt < 4; ++nt) acc[nt] = floatx4{0.f, 0.f, 0.f, 0.f};

        #pragma unroll
        for (int nt = 0; nt < 4; ++nt) {
            const _Float16* bp = &augB[(nt * 16 + l16) * BSTRIDE + quad * 8];
            const half8v b0 = *reinterpret_cast<const half8v*>(bp);
            const half8v b1 = *reinterpret_cast<const half8v*>(bp + 32);
            const half8v b2 = *reinterpret_cast<const half8v*>(bp + 64);
            const half8v b3 = *reinterpret_cast<const half8v*>(bp + 96);
            acc[nt] = __builtin_amdgcn_mfma_f32_16x16x32_f16(b0, a0, acc[nt], 0, 0, 0);
            acc[nt] = __builtin_amdgcn_mfma_f32_16x16x32_f16(b1, a1, acc[nt], 0, 0, 0);
            acc[nt] = __builtin_amdgcn_mfma_f32_16x16x32_f16(b2, s0, acc[nt], 0, 0, 0);
            acc[nt] = __builtin_amdgcn_mfma_f32_16x16x32_f16(b3, s1, acc[nt], 0, 0, 0);
        }

        // ---- Epilogue: C/D col = l16 = agent-row, row = quad*4+reg = e offset.
        // Lane writes 16B at l16*256B + nt*64B + quad*16B: quads form 64B runs,
        // nt pairs complete 128B lines -> L2 merges (plain stores, no nt). ----
        float* o = obase + i * 1024;
        #pragma unroll
        for (int nt = 0; nt < 4; ++nt) {
            floatx4 r;
            #pragma unroll
            for (int reg = 0; reg < 4; ++reg) {
                float y = acc[nt][reg];
                y = fminf(10.f, fmaxf(-10.f, y));
                const float tv  = __builtin_amdgcn_exp2f(y * 2.8853900817779268f); // e^{2y}
                r[reg] = (tv - 1.f) * __builtin_amdgcn_rcpf(tv + 1.f);
            }
            *reinterpret_cast<floatx4*>(o + nt * 16) = r;
        }
    }
}

extern "C" void kernel_launch(void* const* d_in, const int* in_sizes, int n_in,
                              void* d_out, int out_size, void* d_ws, size_t ws_size,
                              hipStream_t stream) {
    const float* x  = (const float*)d_in[0];
    const float* Hw = (const float*)d_in[1];
    const float* Cw = (const float*)d_in[2];
    float* out = (float*)d_out;

    const int rows   = in_sizes[0] / 512;                       // 65536 batch rows
    const int ntiles = rows * 8 / 16;                           // 32768 m-tiles
    const int blocks = ntiles / (WAVES_PER_BLOCK * TILES_PER_WAVE); // 2048
    comm_kernel<<<blocks, 256, 0, stream>>>(x, Hw, Cw, out);
}

// Round 5
// 228.201 us; speedup vs baseline: 1.0628x; 1.0628x over previous
//
#include <hip/hip_runtime.h>

// CommLayer: y[b,a,e] = tanh( xb[b,a,:]·M[e,:] + S[b,:]·Cn[e,:] ),
//   M = H - C/7, Cn = C/7, S[b] = sum_a xb[b,a,:].
// K=128 fp16 MFMA GEMM, A_aug[m=(b,a)] = [xb | S(b)], B_aug[e] = [M[e] | Cn[e]].
// R10: rounds 6-9 proved dur is INVARIANT to within-wave scheduling (four
// different schedules, identical 86us / 2.4 TB/s / idle pipes). New theory:
// grid-scale convoy. 2048 blocks = exactly 8/CU = whole grid resident at t=0,
// zero block churn; all waves issue loads in phase (queues balloon), then all
// compute in phase (memory idles) -- self-sustaining, BW stuck at 38%.
// Test = opposite extreme: TILES_PER_WAVE=1, 8192 short-lived blocks, blocks
// retire & get replaced continuously -> staggered arrivals decorrelate phases.
// Weight staging runs 4x more often but is L2-resident (~8us total @ 34TB/s).
// Kept from earlier rounds: BSTRIDE=144 (bank conflicts = 0, verified R8).
// Prediction: convoy right -> dur 55-65us, hbm_gbps 3200-4000; unchanged ->
// MSHR/line-request cap next (dense LDS-redistributed loads + nt stores).

typedef _Float16 half4v  __attribute__((ext_vector_type(4)));
typedef _Float16 half8v  __attribute__((ext_vector_type(8)));
typedef float    floatx4 __attribute__((ext_vector_type(4)));

#define WAVES_PER_BLOCK 4
#define BSTRIDE 144   // halfs per augB row: 128 + 16 pad (288 B = 32 mod 128)

__device__ __forceinline__ half8v h8_bfly_add(half8v v, int mask) {
    union { half8v h; int i[4]; } u, r;
    u.h = v;
    #pragma unroll
    for (int k = 0; k < 4; ++k) r.i[k] = __shfl_xor(u.i[k], mask, 64);
    return v + r.h;   // v_pk_add_f16 x4
}

__global__ __launch_bounds__(256, 8)
void comm_kernel(const float* __restrict__ x,
                 const float* __restrict__ Hw,
                 const float* __restrict__ Cw,
                 float* __restrict__ out)
{
    __shared__ __align__(16) _Float16 augB[64 * BSTRIDE];  // 18432 B

    const int tid  = threadIdx.x;
    const int lane = tid & 63;
    const int wave = tid >> 6;
    const int quad = lane >> 4;   // 0..3
    const int l16  = lane & 15;

    // ---- Stage 0 (once per block): build augmented B in LDS ----
    // augB[e][k<64] = H[e][k] - C[e][k]/7 ; augB[e][64+k] = C[e][k]/7
    #pragma unroll
    for (int i = 0; i < 4; ++i) {
        const int idx = i * 256 + tid;        // 0..1023 float4-chunks
        const int e = idx >> 4;
        const int k = (idx & 15) << 2;
        const float4 h = *reinterpret_cast<const float4*>(Hw + e * 64 + k);
        const float4 c = *reinterpret_cast<const float4*>(Cw + e * 64 + k);
        half4v m4, c4;
        m4[0] = (_Float16)(h.x - c.x * (1.0f / 7.0f)); c4[0] = (_Float16)(c.x * (1.0f / 7.0f));
        m4[1] = (_Float16)(h.y - c.y * (1.0f / 7.0f)); c4[1] = (_Float16)(c.y * (1.0f / 7.0f));
        m4[2] = (_Float16)(h.z - c.z * (1.0f / 7.0f)); c4[2] = (_Float16)(c.z * (1.0f / 7.0f));
        m4[3] = (_Float16)(h.w - c.w * (1.0f / 7.0f)); c4[3] = (_Float16)(c.w * (1.0f / 7.0f));
        *reinterpret_cast<half4v*>(&augB[e * BSTRIDE + k])      = m4;
        *reinterpret_cast<half4v*>(&augB[e * BSTRIDE + 64 + k]) = c4;
    }
    __syncthreads();   // the only barrier

    const int wgid = blockIdx.x * WAVES_PER_BLOCK + wave;   // one m-tile per wave
    const float* xi = x + (size_t)wgid * 1024 + l16 * 64 + quad * 8;
    float* o = out + (size_t)wgid * 1024 + l16 * 64 + quad * 4;

    // ---- One tile: 4 loads -> convert -> butterfly -> MFMA -> store ----
    const float4 v0 = *reinterpret_cast<const float4*>(xi);
    const float4 v1 = *reinterpret_cast<const float4*>(xi + 4);
    const float4 v2 = *reinterpret_cast<const float4*>(xi + 32);
    const float4 v3 = *reinterpret_cast<const float4*>(xi + 36);

    // ---- x fragments (B-operand layout: n = l16, k = quad*8 + j) ----
    half8v a0, a1;   // kt=0 (k 0..31), kt=1 (k 32..63)
    a0[0]=(_Float16)v0.x; a0[1]=(_Float16)v0.y; a0[2]=(_Float16)v0.z; a0[3]=(_Float16)v0.w;
    a0[4]=(_Float16)v1.x; a0[5]=(_Float16)v1.y; a0[6]=(_Float16)v1.z; a0[7]=(_Float16)v1.w;
    a1[0]=(_Float16)v2.x; a1[1]=(_Float16)v2.y; a1[2]=(_Float16)v2.z; a1[3]=(_Float16)v2.w;
    a1[4]=(_Float16)v3.x; a1[5]=(_Float16)v3.y; a1[6]=(_Float16)v3.z; a1[7]=(_Float16)v3.w;

    // ---- S via packed fp16 butterfly over the 8 agent-lanes (l16 bits 0..2).
    // Result is broadcast to every lane = kt=2,3 augmented fragment. ----
    half8v s0 = a0, s1 = a1;
    #pragma unroll
    for (int m = 1; m <= 4; m <<= 1) {
        s0 = h8_bfly_add(s0, m);
        s1 = h8_bfly_add(s1, m);
    }

    // ---- MFMA, transposed: weights as A-operand ----
    floatx4 acc[4];
    #pragma unroll
    for (int nt = 0; nt < 4; ++nt) acc[nt] = floatx4{0.f, 0.f, 0.f, 0.f};

    #pragma unroll
    for (int nt = 0; nt < 4; ++nt) {
        const _Float16* bp = &augB[(nt * 16 + l16) * BSTRIDE + quad * 8];
        const half8v b0 = *reinterpret_cast<const half8v*>(bp);
        const half8v b1 = *reinterpret_cast<const half8v*>(bp + 32);
        const half8v b2 = *reinterpret_cast<const half8v*>(bp + 64);
        const half8v b3 = *reinterpret_cast<const half8v*>(bp + 96);
        acc[nt] = __builtin_amdgcn_mfma_f32_16x16x32_f16(b0, a0, acc[nt], 0, 0, 0);
        acc[nt] = __builtin_amdgcn_mfma_f32_16x16x32_f16(b1, a1, acc[nt], 0, 0, 0);
        acc[nt] = __builtin_amdgcn_mfma_f32_16x16x32_f16(b2, s0, acc[nt], 0, 0, 0);
        acc[nt] = __builtin_amdgcn_mfma_f32_16x16x32_f16(b3, s1, acc[nt], 0, 0, 0);
    }

    // ---- Epilogue: C/D col = l16 = agent-row, row = quad*4+reg = e offset.
    // Lane writes 16B at l16*256B + nt*64B + quad*16B: quads form 64B runs,
    // nt pairs complete 128B lines -> L2 merges (plain stores, no nt). ----
    #pragma unroll
    for (int nt = 0; nt < 4; ++nt) {
        floatx4 r;
        #pragma unroll
        for (int reg = 0; reg < 4; ++reg) {
            float y = acc[nt][reg];
            y = fminf(10.f, fmaxf(-10.f, y));
            const float tv  = __builtin_amdgcn_exp2f(y * 2.8853900817779268f); // e^{2y}
            r[reg] = (tv - 1.f) * __builtin_amdgcn_rcpf(tv + 1.f);
        }
        *reinterpret_cast<floatx4*>(o + nt * 16) = r;
    }
}

extern "C" void kernel_launch(void* const* d_in, const int* in_sizes, int n_in,
                              void* d_out, int out_size, void* d_ws, size_t ws_size,
                              hipStream_t stream) {
    const float* x  = (const float*)d_in[0];
    const float* Hw = (const float*)d_in[1];
    const float* Cw = (const float*)d_in[2];
    float* out = (float*)d_out;

    const int rows   = in_sizes[0] / 512;        // 65536 batch rows
    const int ntiles = rows * 8 / 16;            // 32768 m-tiles
    const int blocks = ntiles / WAVES_PER_BLOCK; // 8192 blocks, 1 tile/wave
    comm_kernel<<<blocks, 256, 0, stream>>>(x, Hw, Cw, out);
}